// Round 8
// baseline (378.841 us; speedup 1.0000x reference)
//
#include <hip/hip_runtime.h>

#define B_ 2
#define N_ 1569
#define C_ 768
#define H_ 12
#define D_ 64
#define P_ 196
#define F_ 8
#define S_ 1568
#define QKVLD 2304
#define SCALE 0.125f

typedef unsigned short ushort_t;
using short8 = __attribute__((ext_vector_type(8))) short;
using f32x4  = __attribute__((ext_vector_type(4))) float;

__device__ __forceinline__ ushort_t f2bf(float x) {
    unsigned u = __float_as_uint(x);
    u += 0x7fffu + ((u >> 16) & 1);       // RNE
    return (ushort_t)(u >> 16);
}
__device__ __forceinline__ float bf2f(ushort_t h) {
    return __uint_as_float((unsigned)h << 16);
}
__device__ __forceinline__ uint2 pack4(float a, float b, float c, float d) {
    uint2 o;
    o.x = f2bf(a) | ((unsigned)f2bf(b) << 16);
    o.y = f2bf(c) | ((unsigned)f2bf(d) << 16);
    return o;
}
// async 16B global -> LDS DMA (dst must be wave-uniform base + lane*16)
__device__ __forceinline__ void gl2lds16(const void* g, void* l) {
    __builtin_amdgcn_global_load_lds(
        (const __attribute__((address_space(1))) unsigned int*)g,
        (__attribute__((address_space(3))) unsigned int*)l, 16, 0, 0);
}

// ---------------------------------------------------------------------------
// fp32 -> bf16 elementwise convert (n4 = n/4 float4 groups)
// ---------------------------------------------------------------------------
__global__ __launch_bounds__(256)
void cvt_f32_bf16(const float* __restrict__ s, ushort_t* __restrict__ d, int n4)
{
    int i = blockIdx.x * 256 + threadIdx.x;
    if (i < n4) {
        float4 v = ((const float4*)s)[i];
        ((uint2*)d)[i] = pack4(v.x, v.y, v.z, v.w);
    }
}

// ---------------------------------------------------------------------------
// Transpose+convert weights: src (K x ldsrc fp32) -> dst (N x K bf16)
// ---------------------------------------------------------------------------
__global__ __launch_bounds__(256)
void transpose_cvt(const float* __restrict__ src, ushort_t* __restrict__ dst,
                   int K, int ldsrc)
{
    __shared__ float tle[32][33];
    const int n0 = blockIdx.x * 32, k0 = blockIdx.y * 32;
    const int tx = threadIdx.x & 31, ty = threadIdx.x >> 5;
#pragma unroll
    for (int j = 0; j < 4; j++)
        tle[ty + 8 * j][tx] = src[(long)(k0 + ty + 8 * j) * ldsrc + n0 + tx];
    __syncthreads();
#pragma unroll
    for (int j = 0; j < 4; j++)
        dst[(long)(n0 + ty + 8 * j) * K + k0 + tx] = f2bf(tle[tx][ty + 8 * j]);
}

// ---------------------------------------------------------------------------
// bf16 MFMA GEMM: C = alpha*A@Bt^T (+bias). 128x128x32 tile, 256 thr.
// Double-buffered global_load_lds + FRAGMENT-MAJOR LDS:
//   tile chunk layout [mtile(8)][lane(64)][16B]; DMA lane l stages
//   row w*16+(l&15), kseg l>>4 -> dst chunk w*64+l (wave-uniform+lane*16 ok).
//   Fragment ds_read_b128 = base + lane*16 -> 2 lanes/bank, conflict-FREE
//   (r7's row-major layout had 8-way conflicts, 3.6M SQ_LDS_BANK_CONFLICT).
// ---------------------------------------------------------------------------
template<int GATHER, int OUTBF>
__global__ __launch_bounds__(256)
void gemm_bf16(const ushort_t* __restrict__ A, const ushort_t* __restrict__ Bt,
               void* __restrict__ Cv, int M, int Nn, int K,
               float alpha, const float* __restrict__ bias)
{
    // [2 bufs][8 mtiles][64 lanes][8 elems]
    __shared__ ushort_t As[2][4096];
    __shared__ ushort_t Bs[2][4096];

    const int tid = threadIdx.x;
    const int m0 = blockIdx.x * 128, n0 = blockIdx.y * 128;
    const int wave = tid >> 6, lane = tid & 63;
    const int lrow = lane & 15, quad = lane >> 4;

    // staging assignment (fragment-major): row w*16+(lane&15), kseg lane>>4
    const int arow = wave * 16 + lrow;      // 0..63
    const int kseg = quad;                  // 0..3
    int ma0 = m0 + arow;      if (ma0 >= M) ma0 = M - 1;
    int ma1 = m0 + 64 + arow; if (ma1 >= M) ma1 = M - 1;
    long ra0, ra1;
    if (GATHER) {
        ra0 = (long)ma0 * F_ + (ma0 % S_) / P_;
        ra1 = (long)ma1 * F_ + (ma1 % S_) / P_;
    } else { ra0 = ma0; ra1 = ma1; }
    const ushort_t* ap0 = A + ra0 * K + kseg * 8;
    const ushort_t* ap1 = A + ra1 * K + kseg * 8;
    const ushort_t* bp0 = Bt + (long)(n0 + arow) * K + kseg * 8;
    const ushort_t* bp1 = Bt + (long)(n0 + 64 + arow) * K + kseg * 8;
    // dst chunk indices (x8 elements): low rows -> tiles 0..3, high -> 4..7
    const int cA0 = (wave * 64 + lane) * 8;
    const int cA1 = ((4 + wave) * 64 + lane) * 8;

    f32x4 acc[4][4];
#pragma unroll
    for (int i = 0; i < 4; i++)
#pragma unroll
        for (int j = 0; j < 4; j++) acc[i][j] = (f32x4){0.f, 0.f, 0.f, 0.f};

    // prologue: DMA tile 0 into buf 0
    gl2lds16(ap0, &As[0][cA0]);
    gl2lds16(ap1, &As[0][cA1]);
    gl2lds16(bp0, &Bs[0][cA0]);
    gl2lds16(bp1, &Bs[0][cA1]);

    const int tmb = (wave & 1) * 4;   // m-tile base for this wave
    const int tnb = (wave >> 1) * 4;  // n-tile base

    const int nk = K >> 5;
    for (int kt = 0; kt < nk; kt++) {
        const int cur = kt & 1, nxt = cur ^ 1;
        __syncthreads();   // drains DMA for tile kt; prev ds_reads also done
        if (kt + 1 < nk) {
            const int k1 = (kt + 1) * 32;
            gl2lds16(ap0 + k1, &As[nxt][cA0]);
            gl2lds16(ap1 + k1, &As[nxt][cA1]);
            gl2lds16(bp0 + k1, &Bs[nxt][cA0]);
            gl2lds16(bp1 + k1, &Bs[nxt][cA1]);
        }
        short8 af[4], bf[4];
#pragma unroll
        for (int mt = 0; mt < 4; mt++)
            af[mt] = *(const short8*)&As[cur][((tmb + mt) * 64 + lane) * 8];
#pragma unroll
        for (int nt = 0; nt < 4; nt++)
            bf[nt] = *(const short8*)&Bs[cur][((tnb + nt) * 64 + lane) * 8];
#pragma unroll
        for (int mt = 0; mt < 4; mt++)
#pragma unroll
            for (int nt = 0; nt < 4; nt++)
                acc[mt][nt] = __builtin_amdgcn_mfma_f32_16x16x32_bf16(
                    af[mt], bf[nt], acc[mt][nt], 0, 0, 0);
    }

    const int wm = (wave & 1) * 64, wn = (wave >> 1) * 64;
#pragma unroll
    for (int mt = 0; mt < 4; mt++) {
#pragma unroll
        for (int nt = 0; nt < 4; nt++) {
            int row = m0 + wm + mt * 16 + quad * 4;
            int col = n0 + wn + nt * 16 + lrow;
            float bv = bias ? bias[col] : 0.f;
#pragma unroll
            for (int r = 0; r < 4; r++) {
                if (row + r < M) {
                    float v = acc[mt][nt][r] * alpha + bv;
                    if (OUTBF)
                        ((ushort_t*)Cv)[(long)(row + r) * Nn + col] = f2bf(v);
                    else
                        ((float*)Cv)[(long)(row + r) * Nn + col] = v;
                }
            }
        }
    }
}

// ---------------------------------------------------------------------------
// Pre-pass: qkv fp32 -> fragment-major bf16 layouts for barrier-free attn.
// ---------------------------------------------------------------------------
__global__ __launch_bounds__(256)
void prep_kv(const float* __restrict__ qkv, ushort_t* __restrict__ q_bf,
             ushort_t* __restrict__ k_bf, ushort_t* __restrict__ vT_bf)
{
    const int f = blockIdx.x, h = blockIdx.y, b = blockIdx.z;
    const int t = threadIdx.x;
    const long rowbase = (long)(b * N_ + 1 + f * P_) * QKVLD;

    {
        ushort_t* qd = q_bf + ((long)(b * H_ + h) * S_ + f * P_) * 64;
        for (int u = t; u < P_ * 16; u += 256) {
            int row = u >> 4, seg = u & 15;
            float4 v = *(const float4*)(qkv + rowbase + (long)row * QKVLD + h * 64 + seg * 4);
            *(uint2*)(qd + (long)row * 64 + seg * 4) = pack4(v.x, v.y, v.z, v.w);
        }
    }
    {
        ushort_t* kd = k_bf + (long)((b * H_ + h) * F_ + f) * 13312;
        for (int u = t; u < 208 * 16; u += 256) {
            int key = u >> 4, seg = u & 15;
            float4 v = make_float4(0.f, 0.f, 0.f, 0.f);
            if (key < P_)
                v = *(const float4*)(qkv + rowbase + (long)key * QKVLD + 768 + h * 64 + seg * 4);
            int ks = seg >> 3, qq = (seg >> 1) & 3, j0 = (seg & 1) * 4;
            int nt = key >> 4, lr = key & 15;
            *(uint2*)(kd + ((ks * 13 + nt) * 64 + qq * 16 + lr) * 8 + j0)
                = pack4(v.x, v.y, v.z, v.w);
        }
    }
    __shared__ float Vl[224][68];
    for (int u = t; u < 224 * 16; u += 256) {
        int key = u >> 4, seg = u & 15;
        float4 v = make_float4(0.f, 0.f, 0.f, 0.f);
        if (key < P_)
            v = *(const float4*)(qkv + rowbase + (long)key * QKVLD + 1536 + h * 64 + seg * 4);
        *(float4*)&Vl[key][seg * 4] = v;
    }
    __syncthreads();
    {
        ushort_t* vd = vT_bf + (long)((b * H_ + h) * F_ + f) * 14336;
        for (int u = t; u < 64 * 56; u += 256) {
            int d = u / 56, kb = u % 56;
            int s = kb >> 3, qq = (kb >> 1) & 3, j0 = (kb & 1) * 4;
            int nt = d >> 4, lr = d & 15;
            *(uint2*)(vd + ((s * 4 + nt) * 64 + qq * 16 + lr) * 8 + j0) =
                pack4(Vl[kb*4+0][d], Vl[kb*4+1][d], Vl[kb*4+2][d], Vl[kb*4+3][d]);
        }
    }
}

// ---------------------------------------------------------------------------
// Barrier-free MFMA trajectory attention (verified r4).
// ---------------------------------------------------------------------------
__global__ __launch_bounds__(256)
void traj_attn_mfma(const ushort_t* __restrict__ q_bf,
                    const ushort_t* __restrict__ k_bf,
                    const ushort_t* __restrict__ vT_bf,
                    ushort_t* __restrict__ traj)
{
    __shared__ __align__(16) ushort_t Pl[4][7 * 512];

    const int t = threadIdx.x;
    const int wave = t >> 6, lane = t & 63;
    const int lrow = lane & 15, quad = lane >> 4;
    const int qt = blockIdx.x, h = blockIdx.y, b = blockIdx.z;
    const int s0 = qt * 64;
    const bool v12 = (lrow < 4);

    int qrow = s0 + wave * 16 + lrow; if (qrow > S_ - 1) qrow = S_ - 1;
    const ushort_t* qp = q_bf + ((long)(b * H_ + h) * S_ + qrow) * 64 + quad * 8;
    short8 a0 = *(const short8*)qp;
    short8 a1 = *(const short8*)(qp + 32);

    *(uint2*)&Pl[wave][6 * 512 + 256 + lane * 4] = (uint2){0, 0};

    const ushort_t* kfb = k_bf  + (long)((b * H_ + h) * F_) * 13312;
    const ushort_t* vfb = vT_bf + (long)((b * H_ + h) * F_) * 14336;

#pragma unroll 1
    for (int f = 0; f < F_; f++) {
        const ushort_t* kf = kfb + (long)f * 13312;
        const ushort_t* vf = vfb + (long)f * 14336;

        f32x4 acc[13];
#pragma unroll
        for (int nt = 0; nt < 13; nt++) acc[nt] = (f32x4){0.f, 0.f, 0.f, 0.f};
#pragma unroll
        for (int nt = 0; nt < 13; nt++) {
            short8 bv = *(const short8*)(kf + (long)nt * 512 + lane * 8);
            acc[nt] = __builtin_amdgcn_mfma_f32_16x16x32_bf16(a0, bv, acc[nt], 0, 0, 0);
        }
#pragma unroll
        for (int nt = 0; nt < 13; nt++) {
            short8 bv = *(const short8*)(kf + (long)(13 + nt) * 512 + lane * 8);
            acc[nt] = __builtin_amdgcn_mfma_f32_16x16x32_bf16(a1, bv, acc[nt], 0, 0, 0);
        }

        float rl[4];
#pragma unroll
        for (int r = 0; r < 4; r++) {
            float mx = acc[0][r];
#pragma unroll
            for (int nt = 1; nt < 12; nt++) mx = fmaxf(mx, acc[nt][r]);
            if (v12) mx = fmaxf(mx, acc[12][r]);
#pragma unroll
            for (int off = 1; off < 16; off <<= 1)
                mx = fmaxf(mx, __shfl_xor(mx, off, 16));
            float sum = 0.f;
#pragma unroll
            for (int nt = 0; nt < 12; nt++) {
                float w = __expf((acc[nt][r] - mx) * SCALE);
                acc[nt][r] = w; sum += w;
            }
            {
                float w = v12 ? __expf((acc[12][r] - mx) * SCALE) : 0.f;
                acc[12][r] = w; sum += w;
            }
#pragma unroll
            for (int off = 1; off < 16; off <<= 1)
                sum += __shfl_xor(sum, off, 16);
            rl[r] = 1.f / sum;
        }

#pragma unroll
        for (int nt = 0; nt < 13; nt++) {
            int key = nt * 16 + lrow;
            int base = (key >> 5) * 512 + ((key >> 3) & 3) * 128 + (key & 7) + quad * 32;
#pragma unroll
            for (int r = 0; r < 4; r++)
                Pl[wave][base + r * 8] = f2bf(acc[nt][r]);
        }
        asm volatile("s_waitcnt lgkmcnt(0)" ::: "memory");

        f32x4 av[4];
#pragma unroll
        for (int nt = 0; nt < 4; nt++) av[nt] = (f32x4){0.f, 0.f, 0.f, 0.f};
#pragma unroll
        for (int s = 0; s < 7; s++) {
            short8 af = *(const short8*)&Pl[wave][s * 512 + lane * 8];
#pragma unroll
            for (int nt = 0; nt < 4; nt++) {
                short8 bv = *(const short8*)(vf + (long)(s * 4 + nt) * 512 + lane * 8);
                av[nt] = __builtin_amdgcn_mfma_f32_16x16x32_bf16(af, bv, av[nt], 0, 0, 0);
            }
        }

#pragma unroll
        for (int nt = 0; nt < 4; nt++)
#pragma unroll
            for (int r = 0; r < 4; r++) {
                int so = s0 + wave * 16 + quad * 4 + r;
                if (so < S_)
                    traj[((long)(b * S_ + so) * F_ + f) * C_ + h * 64 + nt * 16 + lrow]
                        = f2bf(av[nt][r] * rl[r]);
            }
    }
}

// ---------------------------------------------------------------------------
// CLS attention, split-K flash-style (verified r5).
// ---------------------------------------------------------------------------
#define CLS_CH 13
__global__ __launch_bounds__(256)
void cls_attn_part(const float* __restrict__ qkv, float* __restrict__ part)
{
    const int c = blockIdx.x, hh = blockIdx.y, b = blockIdx.z;
    const int t = threadIdx.x;
    const int n0 = c * 128;
    const int nk = (N_ - n0 < 128) ? (N_ - n0) : 128;

    __shared__ float qs[64];
    __shared__ float sc[128];
    __shared__ float red[256];

    if (t < 64) qs[t] = qkv[(long)(b * N_) * QKVLD + hh * 64 + t];
    __syncthreads();

    if (t < 128) {
        float acc = -1e30f;
        if (t < nk) {
            const float* krow = qkv + (long)(b * N_ + n0 + t) * QKVLD + 768 + hh * 64;
            acc = 0.f;
#pragma unroll
            for (int j4 = 0; j4 < 16; j4++) {
                float4 kv = *(const float4*)(krow + j4 * 4);
                acc = fmaf(kv.x, qs[j4*4+0], acc);
                acc = fmaf(kv.y, qs[j4*4+1], acc);
                acc = fmaf(kv.z, qs[j4*4+2], acc);
                acc = fmaf(kv.w, qs[j4*4+3], acc);
            }
            acc *= SCALE;
        }
        sc[t] = acc;
        red[t] = acc;
    }
    __syncthreads();
    for (int s = 64; s > 0; s >>= 1) {
        if (t < s && t + s < 128) red[t] = fmaxf(red[t], red[t + s]);
        __syncthreads();
    }
    const float m = red[0];
    __syncthreads();

    if (t < 128) {
        float w = (t < nk) ? __expf(sc[t] - m) : 0.f;
        sc[t] = w;
        red[t] = w;
    }
    __syncthreads();
    for (int s = 64; s > 0; s >>= 1) {
        if (t < s && t + s < 128) red[t] += red[t + s];
        __syncthreads();
    }
    const float lsum = red[0];
    __syncthreads();

    const int j = t & 63, grp = t >> 6;
    float acc = 0.f;
    for (int n = grp; n < nk; n += 4)
        acc = fmaf(sc[n], qkv[(long)(b * N_ + n0 + n) * QKVLD + 1536 + hh * 64 + j], acc);
    red[t] = acc;
    __syncthreads();

    float* pp = part + (long)(((b * H_ + hh) * CLS_CH) + c) * 68;
    if (t < 64)
        pp[2 + t] = red[t] + red[64 + t] + red[128 + t] + red[192 + t];
    if (t == 0) { pp[0] = m; pp[1] = lsum; }
}

__global__ __launch_bounds__(64)
void cls_attn_merge(const float* __restrict__ part, float* __restrict__ outcat)
{
    const int bh = blockIdx.x;
    const int b = bh / H_, hh = bh % H_;
    const int t = threadIdx.x;
    const float* pp = part + (long)(bh * CLS_CH) * 68;

    float m = -1e30f;
#pragma unroll
    for (int c = 0; c < CLS_CH; c++) m = fmaxf(m, pp[c * 68]);
    float l = 0.f, o = 0.f;
#pragma unroll
    for (int c = 0; c < CLS_CH; c++) {
        float w = __expf(pp[c * 68] - m);
        l = fmaf(pp[c * 68 + 1], w, l);
        o = fmaf(pp[c * 68 + 2 + t], w, o);
    }
    outcat[(long)(b * N_) * C_ + hh * 64 + t] = o / l;
}

// ---------------------------------------------------------------------------
// Second attention over F=8 + weighted traj sum (verified r4).
// ---------------------------------------------------------------------------
__global__ __launch_bounds__(256)
void attn2_kernel(const float* __restrict__ q2, const ushort_t* __restrict__ k2,
                  const ushort_t* __restrict__ traj, float* __restrict__ outcat,
                  float* __restrict__ attn_out)
{
    const int bs = blockIdx.x;
    const int b = bs / S_, s = bs % S_;
    __shared__ float qs[768];
    __shared__ ushort_t ks[8 * 768];
    __shared__ float logit[12][8];
    __shared__ float wsm[12][8];
    const int t = threadIdx.x;

    const float* qrow = q2 + (long)bs * 768;
    if (t < 192) *(float4*)&qs[t * 4] = *(const float4*)(qrow + t * 4);
    const uint4* krow = (const uint4*)(k2 + (long)bs * 6144);
#pragma unroll
    for (int u = t; u < 768; u += 256)
        *(uint4*)&ks[u * 8] = krow[u];
    __syncthreads();

    if (t < 96) {
        int hh = t >> 3, f = t & 7;
        float acc = 0.f;
#pragma unroll 8
        for (int j = 0; j < 64; j++)
            acc = fmaf(qs[hh * 64 + j], bf2f(ks[f * 768 + hh * 64 + j]), acc);
        logit[hh][f] = acc;
    }
    __syncthreads();
    if (t < 12) {
        float m = logit[t][0];
#pragma unroll
        for (int f = 1; f < 8; f++) m = fmaxf(m, logit[t][f]);
        float w[8], sum = 0.f;
#pragma unroll
        for (int f = 0; f < 8; f++) { w[f] = __expf(logit[t][f] - m); sum += w[f]; }
        float r = 1.f / sum;
#pragma unroll
        for (int f = 0; f < 8; f++) wsm[t][f] = w[f] * r;
    }
    __syncthreads();
    if (t < 96) {
        int hh = t >> 3, f = t & 7;
        attn_out[((long)(b * H_ + hh) * S_ + s) * 8 + f] = wsm[hh][f];
    }
    if (t < 96) {
        const int c0 = t * 8, hh = t >> 3;
        const ushort_t* trow = traj + (long)bs * 6144;
        float o[8];
#pragma unroll
        for (int i = 0; i < 8; i++) o[i] = 0.f;
#pragma unroll
        for (int f = 0; f < 8; f++) {
            uint4 tv = *(const uint4*)(trow + f * 768 + c0);
            float wv = wsm[hh][f];
            const ushort_t* e = (const ushort_t*)&tv;
#pragma unroll
            for (int i = 0; i < 8; i++) o[i] = fmaf(wv, bf2f(e[i]), o[i]);
        }
        float* orow = outcat + ((long)(b * N_) + 1 + s) * 768 + c0;
        *(float4*)orow       = make_float4(o[0], o[1], o[2], o[3]);
        *(float4*)(orow + 4) = make_float4(o[4], o[5], o[6], o[7]);
    }
}

// ---------------------------------------------------------------------------
extern "C" void kernel_launch(void* const* d_in, const int* in_sizes, int n_in,
                              void* d_out, int out_size, void* d_ws, size_t ws_size,
                              hipStream_t stream)
{
    (void)in_sizes; (void)n_in; (void)out_size; (void)ws_size;
    const float* x     = (const float*)d_in[0];
    const float* Wqkv  = (const float*)d_in[1];
    const float* Wpq   = (const float*)d_in[2];
    const float* Wpkv  = (const float*)d_in[3];
    const float* Wproj = (const float*)d_in[4];
    const float* bproj = (const float*)d_in[5];
    float* out = (float*)d_out;

    char* p = (char*)d_ws;
    // region A: qkv f32 (28.9 MB), later overwritten by traj_bf (38.5 MB)
    float*    qkv     = (float*)p;
    ushort_t* traj_bf = (ushort_t*)p;
    p += (size_t)25088 * 768 * 2;
    float* q2 = (float*)p;  p += (size_t)3136 * 768 * 4;
    // region C: [x_bf | q_bf | k_bf | vT_bf] early, k2_bf (38.5 MB) late
    char* c0 = p;
    ushort_t* k2_bf = (ushort_t*)c0;
    ushort_t* x_bf  = (ushort_t*)c0;
    ushort_t* q_bf  = (ushort_t*)(c0 + (size_t)4819968);
    ushort_t* k_bf  = (ushort_t*)(c0 + (size_t)4819968 + 4816896);
    ushort_t* vT_bf = (ushort_t*)(c0 + (size_t)4819968 + 4816896 + 5111808);
    p += (size_t)25088 * 768 * 2;
    float*    outcat    = (float*)p;     p += (size_t)3138 * 768 * 4;
    ushort_t* outcat_bf = (ushort_t*)p;  p += (size_t)3138 * 768 * 2;
    ushort_t* Wqkv_t  = (ushort_t*)p;    p += (size_t)1769472 * 2;
    ushort_t* Wpq_t   = (ushort_t*)p;    p += (size_t)589824 * 2;
    ushort_t* Wpkv_t  = (ushort_t*)p;    p += (size_t)589824 * 2;
    ushort_t* Wproj_t = (ushort_t*)p;    p += (size_t)589824 * 2;
    float*    cls_part = (float*)p;      p += (size_t)24 * CLS_CH * 68 * 4;
    float* attn_out = out + (size_t)3138 * 768;

    // input conversions
    cvt_f32_bf16<<<2354, 256, 0, stream>>>(x, x_bf, 602496);
    transpose_cvt<<<dim3(72, 24), 256, 0, stream>>>(Wqkv,  Wqkv_t,  768, 2304);
    transpose_cvt<<<dim3(24, 24), 256, 0, stream>>>(Wpq,   Wpq_t,   768, 768);
    transpose_cvt<<<dim3(24, 24), 256, 0, stream>>>(Wpkv,  Wpkv_t,  768, 1536);
    transpose_cvt<<<dim3(24, 24), 256, 0, stream>>>(Wproj, Wproj_t, 768, 768);

    // 1. qkv = x @ W_qkv  (fp32 out)
    gemm_bf16<0, 0><<<dim3(25, 18), 256, 0, stream>>>(x_bf, Wqkv_t, qkv, 3138, 2304, 768, 1.f, nullptr);
    // 2. reshape to fragment-major bf16 layouts
    prep_kv<<<dim3(8, 12, 2), 256, 0, stream>>>(qkv, q_bf, k_bf, vT_bf);
    // 3. CLS attention (split-K) -> outcat row 0 (last reader of fp32 qkv)
    cls_attn_part<<<dim3(CLS_CH, 12, 2), 256, 0, stream>>>(qkv, cls_part);
    cls_attn_merge<<<24, 64, 0, stream>>>(cls_part, outcat);
    // 4. barrier-free MFMA trajectory attention -> traj_bf (overwrites qkv)
    traj_attn_mfma<<<dim3(25, 12, 2), 256, 0, stream>>>(q_bf, k_bf, vT_bf, traj_bf);
    // 5. q2 = (x_diag @ W_pq) * scale
    gemm_bf16<1, 0><<<dim3(25, 6), 256, 0, stream>>>(traj_bf, Wpq_t, q2, 3136, 768, 768, SCALE, nullptr);
    // 6. k2 = traj @ W_pkv[:, :768] -> bf16 (overwrites x/q/k/vT buffers)
    gemm_bf16<0, 1><<<dim3(196, 6), 256, 0, stream>>>(traj_bf, Wpkv_t, k2_bf, 25088, 768, 768, 1.f, nullptr);
    // 7. F-attention + weighted traj sum
    attn2_kernel<<<3136, 256, 0, stream>>>(q2, k2_bf, traj_bf, outcat, attn_out);
    // 8. out = outcat @ W_proj + b_proj
    cvt_f32_bf16<<<2354, 256, 0, stream>>>(outcat, outcat_bf, 602496);
    gemm_bf16<0, 0><<<dim3(25, 6), 256, 0, stream>>>(outcat_bf, Wproj_t, out, 3138, 768, 768, 1.f, bproj);
}

// Round 9
// 348.577 us; speedup vs baseline: 1.0868x; 1.0868x over previous
//
#include <hip/hip_runtime.h>

#define B_ 2
#define N_ 1569
#define C_ 768
#define H_ 12
#define D_ 64
#define P_ 196
#define F_ 8
#define S_ 1568
#define QKVLD 2304
#define SCALE 0.125f

typedef unsigned short ushort_t;
using short8 = __attribute__((ext_vector_type(8))) short;
using f32x4  = __attribute__((ext_vector_type(4))) float;

__device__ __forceinline__ ushort_t f2bf(float x) {
    unsigned u = __float_as_uint(x);
    u += 0x7fffu + ((u >> 16) & 1);       // RNE
    return (ushort_t)(u >> 16);
}
__device__ __forceinline__ float bf2f(ushort_t h) {
    return __uint_as_float((unsigned)h << 16);
}
__device__ __forceinline__ uint2 pack4(float a, float b, float c, float d) {
    uint2 o;
    o.x = f2bf(a) | ((unsigned)f2bf(b) << 16);
    o.y = f2bf(c) | ((unsigned)f2bf(d) << 16);
    return o;
}
// async 16B global -> LDS DMA (dst must be wave-uniform base + lane*16)
__device__ __forceinline__ void gl2lds16(const void* g, void* l) {
    __builtin_amdgcn_global_load_lds(
        (const __attribute__((address_space(1))) unsigned int*)g,
        (__attribute__((address_space(3))) unsigned int*)l, 16, 0, 0);
}

// ---------------------------------------------------------------------------
// fp32 -> bf16 elementwise convert (n4 = n/4 float4 groups)
// ---------------------------------------------------------------------------
__global__ __launch_bounds__(256)
void cvt_f32_bf16(const float* __restrict__ s, ushort_t* __restrict__ d, int n4)
{
    int i = blockIdx.x * 256 + threadIdx.x;
    if (i < n4) {
        float4 v = ((const float4*)s)[i];
        ((uint2*)d)[i] = pack4(v.x, v.y, v.z, v.w);
    }
}

// ---------------------------------------------------------------------------
// Transpose+convert weights: src (K x ldsrc fp32) -> dst (N x K bf16)
// ---------------------------------------------------------------------------
__global__ __launch_bounds__(256)
void transpose_cvt(const float* __restrict__ src, ushort_t* __restrict__ dst,
                   int K, int ldsrc)
{
    __shared__ float tle[32][33];
    const int n0 = blockIdx.x * 32, k0 = blockIdx.y * 32;
    const int tx = threadIdx.x & 31, ty = threadIdx.x >> 5;
#pragma unroll
    for (int j = 0; j < 4; j++)
        tle[ty + 8 * j][tx] = src[(long)(k0 + ty + 8 * j) * ldsrc + n0 + tx];
    __syncthreads();
#pragma unroll
    for (int j = 0; j < 4; j++)
        dst[(long)(n0 + ty + 8 * j) * K + k0 + tx] = f2bf(tle[tx][ty + 8 * j]);
}

// ---------------------------------------------------------------------------
// bf16 MFMA GEMM: C = alpha*A@Bt^T (+bias). 128x128x32 tile, 256 thr.
// Double-buffered global_load_lds (r7) + XOR-SWIZZLED row-major LDS:
//   row r's k-seg s stored at column position s ^ ((r>>1)&3). Swizzle is
//   applied on the SOURCE pointer (same 64B row granule per 4-lane group ->
//   coalescing preserved); DMA dst stays uniform + lane*16. Fragment reads
//   at col = quad ^ ((lrow>>1)&3): 8-lane phases hit 8 distinct 4-bank
//   groups -> conflict-free (r7 row-major had 3.6M SQ_LDS_BANK_CONFLICT,
//   r8 fragment-major killed conflicts but broke global coalescing).
// ---------------------------------------------------------------------------
template<int GATHER, int OUTBF>
__global__ __launch_bounds__(256)
void gemm_bf16(const ushort_t* __restrict__ A, const ushort_t* __restrict__ Bt,
               void* __restrict__ Cv, int M, int Nn, int K,
               float alpha, const float* __restrict__ bias)
{
    __shared__ ushort_t As[2][128][32];
    __shared__ ushort_t Bs[2][128][32];

    const int tid = threadIdx.x;
    const int m0 = blockIdx.x * 128, n0 = blockIdx.y * 128;
    const int wave = tid >> 6, lane = tid & 63;
    const int wm = (wave & 1) * 64, wn = (wave >> 1) * 64;
    const int lrow = lane & 15, quad = lane >> 4;

    // staging: thread covers rows srow, srow+64; stored pos sseg; source seg
    // sw = sseg ^ ((srow>>1)&3)  (rows r and r+64 share the swizzle factor)
    const int srow = tid >> 2, sseg = tid & 3;
    const int sw = sseg ^ ((srow >> 1) & 3);
    int ma0 = m0 + srow;      if (ma0 >= M) ma0 = M - 1;
    int ma1 = m0 + 64 + srow; if (ma1 >= M) ma1 = M - 1;
    long ra0, ra1;
    if (GATHER) {
        ra0 = (long)ma0 * F_ + (ma0 % S_) / P_;
        ra1 = (long)ma1 * F_ + (ma1 % S_) / P_;
    } else { ra0 = ma0; ra1 = ma1; }
    const ushort_t* ap0 = A + ra0 * K + sw * 8;
    const ushort_t* ap1 = A + ra1 * K + sw * 8;
    const ushort_t* bp0 = Bt + (long)(n0 + srow) * K + sw * 8;
    const ushort_t* bp1 = Bt + (long)(n0 + 64 + srow) * K + sw * 8;

    f32x4 acc[4][4];
#pragma unroll
    for (int i = 0; i < 4; i++)
#pragma unroll
        for (int j = 0; j < 4; j++) acc[i][j] = (f32x4){0.f, 0.f, 0.f, 0.f};

    // prologue: DMA tile 0 into buf 0 (dst = uniform + lane*16)
    gl2lds16(ap0, &As[0][srow][sseg * 8]);
    gl2lds16(ap1, &As[0][64 + srow][sseg * 8]);
    gl2lds16(bp0, &Bs[0][srow][sseg * 8]);
    gl2lds16(bp1, &Bs[0][64 + srow][sseg * 8]);

    // fragment-read swizzled column (loop-invariant; (row>>1)&3 == (lrow>>1)&3
    // for 16-aligned tile bases)
    const int csw = (quad ^ ((lrow >> 1) & 3)) * 8;

    const int nk = K >> 5;
    for (int kt = 0; kt < nk; kt++) {
        const int cur = kt & 1, nxt = cur ^ 1;
        __syncthreads();   // drains DMA for tile kt; prev ds_reads also done
        if (kt + 1 < nk) {
            const int k1 = (kt + 1) * 32;
            gl2lds16(ap0 + k1, &As[nxt][srow][sseg * 8]);
            gl2lds16(ap1 + k1, &As[nxt][64 + srow][sseg * 8]);
            gl2lds16(bp0 + k1, &Bs[nxt][srow][sseg * 8]);
            gl2lds16(bp1 + k1, &Bs[nxt][64 + srow][sseg * 8]);
        }
        short8 af[4], bf[4];
#pragma unroll
        for (int mt = 0; mt < 4; mt++)
            af[mt] = *(const short8*)&As[cur][wm + mt * 16 + lrow][csw];
#pragma unroll
        for (int nt = 0; nt < 4; nt++)
            bf[nt] = *(const short8*)&Bs[cur][wn + nt * 16 + lrow][csw];
#pragma unroll
        for (int mt = 0; mt < 4; mt++)
#pragma unroll
            for (int nt = 0; nt < 4; nt++)
                acc[mt][nt] = __builtin_amdgcn_mfma_f32_16x16x32_bf16(
                    af[mt], bf[nt], acc[mt][nt], 0, 0, 0);
    }

#pragma unroll
    for (int mt = 0; mt < 4; mt++) {
#pragma unroll
        for (int nt = 0; nt < 4; nt++) {
            int row = m0 + wm + mt * 16 + quad * 4;
            int col = n0 + wn + nt * 16 + lrow;
            float bv = bias ? bias[col] : 0.f;
#pragma unroll
            for (int r = 0; r < 4; r++) {
                if (row + r < M) {
                    float v = acc[mt][nt][r] * alpha + bv;
                    if (OUTBF)
                        ((ushort_t*)Cv)[(long)(row + r) * Nn + col] = f2bf(v);
                    else
                        ((float*)Cv)[(long)(row + r) * Nn + col] = v;
                }
            }
        }
    }
}

// ---------------------------------------------------------------------------
// Pre-pass: qkv fp32 -> fragment-major bf16 layouts for barrier-free attn.
// ---------------------------------------------------------------------------
__global__ __launch_bounds__(256)
void prep_kv(const float* __restrict__ qkv, ushort_t* __restrict__ q_bf,
             ushort_t* __restrict__ k_bf, ushort_t* __restrict__ vT_bf)
{
    const int f = blockIdx.x, h = blockIdx.y, b = blockIdx.z;
    const int t = threadIdx.x;
    const long rowbase = (long)(b * N_ + 1 + f * P_) * QKVLD;

    {
        ushort_t* qd = q_bf + ((long)(b * H_ + h) * S_ + f * P_) * 64;
        for (int u = t; u < P_ * 16; u += 256) {
            int row = u >> 4, seg = u & 15;
            float4 v = *(const float4*)(qkv + rowbase + (long)row * QKVLD + h * 64 + seg * 4);
            *(uint2*)(qd + (long)row * 64 + seg * 4) = pack4(v.x, v.y, v.z, v.w);
        }
    }
    {
        ushort_t* kd = k_bf + (long)((b * H_ + h) * F_ + f) * 13312;
        for (int u = t; u < 208 * 16; u += 256) {
            int key = u >> 4, seg = u & 15;
            float4 v = make_float4(0.f, 0.f, 0.f, 0.f);
            if (key < P_)
                v = *(const float4*)(qkv + rowbase + (long)key * QKVLD + 768 + h * 64 + seg * 4);
            int ks = seg >> 3, qq = (seg >> 1) & 3, j0 = (seg & 1) * 4;
            int nt = key >> 4, lr = key & 15;
            *(uint2*)(kd + ((ks * 13 + nt) * 64 + qq * 16 + lr) * 8 + j0)
                = pack4(v.x, v.y, v.z, v.w);
        }
    }
    __shared__ float Vl[224][68];
    for (int u = t; u < 224 * 16; u += 256) {
        int key = u >> 4, seg = u & 15;
        float4 v = make_float4(0.f, 0.f, 0.f, 0.f);
        if (key < P_)
            v = *(const float4*)(qkv + rowbase + (long)key * QKVLD + 1536 + h * 64 + seg * 4);
        *(float4*)&Vl[key][seg * 4] = v;
    }
    __syncthreads();
    {
        ushort_t* vd = vT_bf + (long)((b * H_ + h) * F_ + f) * 14336;
        for (int u = t; u < 64 * 56; u += 256) {
            int d = u / 56, kb = u % 56;
            int s = kb >> 3, qq = (kb >> 1) & 3, j0 = (kb & 1) * 4;
            int nt = d >> 4, lr = d & 15;
            *(uint2*)(vd + ((s * 4 + nt) * 64 + qq * 16 + lr) * 8 + j0) =
                pack4(Vl[kb*4+0][d], Vl[kb*4+1][d], Vl[kb*4+2][d], Vl[kb*4+3][d]);
        }
    }
}

// ---------------------------------------------------------------------------
// Barrier-free MFMA trajectory attention (verified r4).
// ---------------------------------------------------------------------------
__global__ __launch_bounds__(256)
void traj_attn_mfma(const ushort_t* __restrict__ q_bf,
                    const ushort_t* __restrict__ k_bf,
                    const ushort_t* __restrict__ vT_bf,
                    ushort_t* __restrict__ traj)
{
    __shared__ __align__(16) ushort_t Pl[4][7 * 512];

    const int t = threadIdx.x;
    const int wave = t >> 6, lane = t & 63;
    const int lrow = lane & 15, quad = lane >> 4;
    const int qt = blockIdx.x, h = blockIdx.y, b = blockIdx.z;
    const int s0 = qt * 64;
    const bool v12 = (lrow < 4);

    int qrow = s0 + wave * 16 + lrow; if (qrow > S_ - 1) qrow = S_ - 1;
    const ushort_t* qp = q_bf + ((long)(b * H_ + h) * S_ + qrow) * 64 + quad * 8;
    short8 a0 = *(const short8*)qp;
    short8 a1 = *(const short8*)(qp + 32);

    *(uint2*)&Pl[wave][6 * 512 + 256 + lane * 4] = (uint2){0, 0};

    const ushort_t* kfb = k_bf  + (long)((b * H_ + h) * F_) * 13312;
    const ushort_t* vfb = vT_bf + (long)((b * H_ + h) * F_) * 14336;

#pragma unroll 1
    for (int f = 0; f < F_; f++) {
        const ushort_t* kf = kfb + (long)f * 13312;
        const ushort_t* vf = vfb + (long)f * 14336;

        f32x4 acc[13];
#pragma unroll
        for (int nt = 0; nt < 13; nt++) acc[nt] = (f32x4){0.f, 0.f, 0.f, 0.f};
#pragma unroll
        for (int nt = 0; nt < 13; nt++) {
            short8 bv = *(const short8*)(kf + (long)nt * 512 + lane * 8);
            acc[nt] = __builtin_amdgcn_mfma_f32_16x16x32_bf16(a0, bv, acc[nt], 0, 0, 0);
        }
#pragma unroll
        for (int nt = 0; nt < 13; nt++) {
            short8 bv = *(const short8*)(kf + (long)(13 + nt) * 512 + lane * 8);
            acc[nt] = __builtin_amdgcn_mfma_f32_16x16x32_bf16(a1, bv, acc[nt], 0, 0, 0);
        }

        float rl[4];
#pragma unroll
        for (int r = 0; r < 4; r++) {
            float mx = acc[0][r];
#pragma unroll
            for (int nt = 1; nt < 12; nt++) mx = fmaxf(mx, acc[nt][r]);
            if (v12) mx = fmaxf(mx, acc[12][r]);
#pragma unroll
            for (int off = 1; off < 16; off <<= 1)
                mx = fmaxf(mx, __shfl_xor(mx, off, 16));
            float sum = 0.f;
#pragma unroll
            for (int nt = 0; nt < 12; nt++) {
                float w = __expf((acc[nt][r] - mx) * SCALE);
                acc[nt][r] = w; sum += w;
            }
            {
                float w = v12 ? __expf((acc[12][r] - mx) * SCALE) : 0.f;
                acc[12][r] = w; sum += w;
            }
#pragma unroll
            for (int off = 1; off < 16; off <<= 1)
                sum += __shfl_xor(sum, off, 16);
            rl[r] = 1.f / sum;
        }

#pragma unroll
        for (int nt = 0; nt < 13; nt++) {
            int key = nt * 16 + lrow;
            int base = (key >> 5) * 512 + ((key >> 3) & 3) * 128 + (key & 7) + quad * 32;
#pragma unroll
            for (int r = 0; r < 4; r++)
                Pl[wave][base + r * 8] = f2bf(acc[nt][r]);
        }
        asm volatile("s_waitcnt lgkmcnt(0)" ::: "memory");

        f32x4 av[4];
#pragma unroll
        for (int nt = 0; nt < 4; nt++) av[nt] = (f32x4){0.f, 0.f, 0.f, 0.f};
#pragma unroll
        for (int s = 0; s < 7; s++) {
            short8 af = *(const short8*)&Pl[wave][s * 512 + lane * 8];
#pragma unroll
            for (int nt = 0; nt < 4; nt++) {
                short8 bv = *(const short8*)(vf + (long)(s * 4 + nt) * 512 + lane * 8);
                av[nt] = __builtin_amdgcn_mfma_f32_16x16x32_bf16(af, bv, av[nt], 0, 0, 0);
            }
        }

#pragma unroll
        for (int nt = 0; nt < 4; nt++)
#pragma unroll
            for (int r = 0; r < 4; r++) {
                int so = s0 + wave * 16 + quad * 4 + r;
                if (so < S_)
                    traj[((long)(b * S_ + so) * F_ + f) * C_ + h * 64 + nt * 16 + lrow]
                        = f2bf(av[nt][r] * rl[r]);
            }
    }
}

// ---------------------------------------------------------------------------
// CLS attention, split-K flash-style (verified r5).
// ---------------------------------------------------------------------------
#define CLS_CH 13
__global__ __launch_bounds__(256)
void cls_attn_part(const float* __restrict__ qkv, float* __restrict__ part)
{
    const int c = blockIdx.x, hh = blockIdx.y, b = blockIdx.z;
    const int t = threadIdx.x;
    const int n0 = c * 128;
    const int nk = (N_ - n0 < 128) ? (N_ - n0) : 128;

    __shared__ float qs[64];
    __shared__ float sc[128];
    __shared__ float red[256];

    if (t < 64) qs[t] = qkv[(long)(b * N_) * QKVLD + hh * 64 + t];
    __syncthreads();

    if (t < 128) {
        float acc = -1e30f;
        if (t < nk) {
            const float* krow = qkv + (long)(b * N_ + n0 + t) * QKVLD + 768 + hh * 64;
            acc = 0.f;
#pragma unroll
            for (int j4 = 0; j4 < 16; j4++) {
                float4 kv = *(const float4*)(krow + j4 * 4);
                acc = fmaf(kv.x, qs[j4*4+0], acc);
                acc = fmaf(kv.y, qs[j4*4+1], acc);
                acc = fmaf(kv.z, qs[j4*4+2], acc);
                acc = fmaf(kv.w, qs[j4*4+3], acc);
            }
            acc *= SCALE;
        }
        sc[t] = acc;
        red[t] = acc;
    }
    __syncthreads();
    for (int s = 64; s > 0; s >>= 1) {
        if (t < s && t + s < 128) red[t] = fmaxf(red[t], red[t + s]);
        __syncthreads();
    }
    const float m = red[0];
    __syncthreads();

    if (t < 128) {
        float w = (t < nk) ? __expf(sc[t] - m) : 0.f;
        sc[t] = w;
        red[t] = w;
    }
    __syncthreads();
    for (int s = 64; s > 0; s >>= 1) {
        if (t < s && t + s < 128) red[t] += red[t + s];
        __syncthreads();
    }
    const float lsum = red[0];
    __syncthreads();

    const int j = t & 63, grp = t >> 6;
    float acc = 0.f;
    for (int n = grp; n < nk; n += 4)
        acc = fmaf(sc[n], qkv[(long)(b * N_ + n0 + n) * QKVLD + 1536 + hh * 64 + j], acc);
    red[t] = acc;
    __syncthreads();

    float* pp = part + (long)(((b * H_ + hh) * CLS_CH) + c) * 68;
    if (t < 64)
        pp[2 + t] = red[t] + red[64 + t] + red[128 + t] + red[192 + t];
    if (t == 0) { pp[0] = m; pp[1] = lsum; }
}

__global__ __launch_bounds__(64)
void cls_attn_merge(const float* __restrict__ part, float* __restrict__ outcat)
{
    const int bh = blockIdx.x;
    const int b = bh / H_, hh = bh % H_;
    const int t = threadIdx.x;
    const float* pp = part + (long)(bh * CLS_CH) * 68;

    float m = -1e30f;
#pragma unroll
    for (int c = 0; c < CLS_CH; c++) m = fmaxf(m, pp[c * 68]);
    float l = 0.f, o = 0.f;
#pragma unroll
    for (int c = 0; c < CLS_CH; c++) {
        float w = __expf(pp[c * 68] - m);
        l = fmaf(pp[c * 68 + 1], w, l);
        o = fmaf(pp[c * 68 + 2 + t], w, o);
    }
    outcat[(long)(b * N_) * C_ + hh * 64 + t] = o / l;
}

// ---------------------------------------------------------------------------
// Second attention over F=8 + weighted traj sum (verified r4).
// ---------------------------------------------------------------------------
__global__ __launch_bounds__(256)
void attn2_kernel(const float* __restrict__ q2, const ushort_t* __restrict__ k2,
                  const ushort_t* __restrict__ traj, float* __restrict__ outcat,
                  float* __restrict__ attn_out)
{
    const int bs = blockIdx.x;
    const int b = bs / S_, s = bs % S_;
    __shared__ float qs[768];
    __shared__ ushort_t ks[8 * 768];
    __shared__ float logit[12][8];
    __shared__ float wsm[12][8];
    const int t = threadIdx.x;

    const float* qrow = q2 + (long)bs * 768;
    if (t < 192) *(float4*)&qs[t * 4] = *(const float4*)(qrow + t * 4);
    const uint4* krow = (const uint4*)(k2 + (long)bs * 6144);
#pragma unroll
    for (int u = t; u < 768; u += 256)
        *(uint4*)&ks[u * 8] = krow[u];
    __syncthreads();

    if (t < 96) {
        int hh = t >> 3, f = t & 7;
        float acc = 0.f;
#pragma unroll 8
        for (int j = 0; j < 64; j++)
            acc = fmaf(qs[hh * 64 + j], bf2f(ks[f * 768 + hh * 64 + j]), acc);
        logit[hh][f] = acc;
    }
    __syncthreads();
    if (t < 12) {
        float m = logit[t][0];
#pragma unroll
        for (int f = 1; f < 8; f++) m = fmaxf(m, logit[t][f]);
        float w[8], sum = 0.f;
#pragma unroll
        for (int f = 0; f < 8; f++) { w[f] = __expf(logit[t][f] - m); sum += w[f]; }
        float r = 1.f / sum;
#pragma unroll
        for (int f = 0; f < 8; f++) wsm[t][f] = w[f] * r;
    }
    __syncthreads();
    if (t < 96) {
        int hh = t >> 3, f = t & 7;
        attn_out[((long)(b * H_ + hh) * S_ + s) * 8 + f] = wsm[hh][f];
    }
    if (t < 96) {
        const int c0 = t * 8, hh = t >> 3;
        const ushort_t* trow = traj + (long)bs * 6144;
        float o[8];
#pragma unroll
        for (int i = 0; i < 8; i++) o[i] = 0.f;
#pragma unroll
        for (int f = 0; f < 8; f++) {
            uint4 tv = *(const uint4*)(trow + f * 768 + c0);
            float wv = wsm[hh][f];
            const ushort_t* e = (const ushort_t*)&tv;
#pragma unroll
            for (int i = 0; i < 8; i++) o[i] = fmaf(wv, bf2f(e[i]), o[i]);
        }
        float* orow = outcat + ((long)(b * N_) + 1 + s) * 768 + c0;
        *(float4*)orow       = make_float4(o[0], o[1], o[2], o[3]);
        *(float4*)(orow + 4) = make_float4(o[4], o[5], o[6], o[7]);
    }
}

// ---------------------------------------------------------------------------
extern "C" void kernel_launch(void* const* d_in, const int* in_sizes, int n_in,
                              void* d_out, int out_size, void* d_ws, size_t ws_size,
                              hipStream_t stream)
{
    (void)in_sizes; (void)n_in; (void)out_size; (void)ws_size;
    const float* x     = (const float*)d_in[0];
    const float* Wqkv  = (const float*)d_in[1];
    const float* Wpq   = (const float*)d_in[2];
    const float* Wpkv  = (const float*)d_in[3];
    const float* Wproj = (const float*)d_in[4];
    const float* bproj = (const float*)d_in[5];
    float* out = (float*)d_out;

    char* p = (char*)d_ws;
    // region A: qkv f32 (28.9 MB), later overwritten by traj_bf (38.5 MB)
    float*    qkv     = (float*)p;
    ushort_t* traj_bf = (ushort_t*)p;
    p += (size_t)25088 * 768 * 2;
    float* q2 = (float*)p;  p += (size_t)3136 * 768 * 4;
    // region C: [x_bf | q_bf | k_bf | vT_bf] early, k2_bf (38.5 MB) late
    char* c0 = p;
    ushort_t* k2_bf = (ushort_t*)c0;
    ushort_t* x_bf  = (ushort_t*)c0;
    ushort_t* q_bf  = (ushort_t*)(c0 + (size_t)4819968);
    ushort_t* k_bf  = (ushort_t*)(c0 + (size_t)4819968 + 4816896);
    ushort_t* vT_bf = (ushort_t*)(c0 + (size_t)4819968 + 4816896 + 5111808);
    p += (size_t)25088 * 768 * 2;
    float*    outcat    = (float*)p;     p += (size_t)3138 * 768 * 4;
    ushort_t* outcat_bf = (ushort_t*)p;  p += (size_t)3138 * 768 * 2;
    ushort_t* Wqkv_t  = (ushort_t*)p;    p += (size_t)1769472 * 2;
    ushort_t* Wpq_t   = (ushort_t*)p;    p += (size_t)589824 * 2;
    ushort_t* Wpkv_t  = (ushort_t*)p;    p += (size_t)589824 * 2;
    ushort_t* Wproj_t = (ushort_t*)p;    p += (size_t)589824 * 2;
    float*    cls_part = (float*)p;      p += (size_t)24 * CLS_CH * 68 * 4;
    float* attn_out = out + (size_t)3138 * 768;

    // input conversions
    cvt_f32_bf16<<<2354, 256, 0, stream>>>(x, x_bf, 602496);
    transpose_cvt<<<dim3(72, 24), 256, 0, stream>>>(Wqkv,  Wqkv_t,  768, 2304);
    transpose_cvt<<<dim3(24, 24), 256, 0, stream>>>(Wpq,   Wpq_t,   768, 768);
    transpose_cvt<<<dim3(24, 24), 256, 0, stream>>>(Wpkv,  Wpkv_t,  768, 1536);
    transpose_cvt<<<dim3(24, 24), 256, 0, stream>>>(Wproj, Wproj_t, 768, 768);

    // 1. qkv = x @ W_qkv  (fp32 out)
    gemm_bf16<0, 0><<<dim3(25, 18), 256, 0, stream>>>(x_bf, Wqkv_t, qkv, 3138, 2304, 768, 1.f, nullptr);
    // 2. reshape to fragment-major bf16 layouts
    prep_kv<<<dim3(8, 12, 2), 256, 0, stream>>>(qkv, q_bf, k_bf, vT_bf);
    // 3. CLS attention (split-K) -> outcat row 0 (last reader of fp32 qkv)
    cls_attn_part<<<dim3(CLS_CH, 12, 2), 256, 0, stream>>>(qkv, cls_part);
    cls_attn_merge<<<24, 64, 0, stream>>>(cls_part, outcat);
    // 4. barrier-free MFMA trajectory attention -> traj_bf (overwrites qkv)
    traj_attn_mfma<<<dim3(25, 12, 2), 256, 0, stream>>>(q_bf, k_bf, vT_bf, traj_bf);
    // 5. q2 = (x_diag @ W_pq) * scale
    gemm_bf16<1, 0><<<dim3(25, 6), 256, 0, stream>>>(traj_bf, Wpq_t, q2, 3136, 768, 768, SCALE, nullptr);
    // 6. k2 = traj @ W_pkv[:, :768] -> bf16 (overwrites x/q/k/vT buffers)
    gemm_bf16<0, 1><<<dim3(196, 6), 256, 0, stream>>>(traj_bf, Wpkv_t, k2_bf, 25088, 768, 768, 1.f, nullptr);
    // 7. F-attention + weighted traj sum
    attn2_kernel<<<3136, 256, 0, stream>>>(q2, k2_bf, traj_bf, outcat, attn_out);
    // 8. out = outcat @ W_proj + b_proj
    cvt_f32_bf16<<<2354, 256, 0, stream>>>(outcat, outcat_bf, 602496);
    gemm_bf16<0, 0><<<dim3(25, 6), 256, 0, stream>>>(outcat_bf, Wproj_t, out, 3138, 768, 768, 1.f, bproj);
}